// Round 2
// baseline (288.873 us; speedup 1.0000x reference)
//
#include <hip/hip_runtime.h>

// Inverse DWT (DB4, periodization) along axes 1,2,3 of (4,256,256,256) fp32.
// Polyphase form:
//   y[2m]   = sum_j s[(m+j-3)&127]*a[j] + w[(m+j-3)&127]*c[j]
//   y[2m+1] = sum_j s[(m+j-3)&127]*b[j] + w[(m+j-3)&127]*d[j]
// with a[j]=h[6-2j], b[j]=h[7-2j], c[j]=h[2j+1], d[j]=-h[2j].

#define FILT_DECL(h)                                          \
  const float a0 = h[6], a1 = h[4], a2 = h[2], a3 = h[0];     \
  const float b0 = h[7], b1 = h[5], b2 = h[3], b3 = h[1];     \
  const float c0 = h[1], c1 = h[3], c2 = h[5], c3 = h[7];     \
  const float d0 = -h[0], d1 = -h[2], d2 = -h[4], d3 = -h[6];

#define Y0(s0,s1,s2,s3,w0,w1,w2,w3)                                        \
  fmaf(w3, c3, fmaf(w2, c2, fmaf(w1, c1, fmaf(w0, c0,                      \
  fmaf(s3, a3, fmaf(s2, a2, fmaf(s1, a1, s0 * a0)))))))
#define Y1(s0,s1,s2,s3,w0,w1,w2,w3)                                        \
  fmaf(w3, d3, fmaf(w2, d2, fmaf(w1, d1, fmaf(w0, d0,                      \
  fmaf(s3, b3, fmaf(s2, b2, fmaf(s1, b1, s0 * b0)))))))

// ---------------- axis 1 (stride 65536), in -> out ----------------
__global__ __launch_bounds__(256) void wav_axis1(const float* __restrict__ in,
                                                 float* __restrict__ out,
                                                 const float* __restrict__ h) {
  const int inner = blockIdx.x * 256 + threadIdx.x;          // d2*d3 flat
  const int m0 = blockIdx.y * 64;                            // m segment
  const size_t base = (size_t)blockIdx.z * (256u * 65536u) + (unsigned)inner;
  const float* __restrict__ ps = in + base;                  // s half: rows 0..127
  const float* __restrict__ pw = in + base + (size_t)128 * 65536;
  float* __restrict__ po = out + base;
  FILT_DECL(h)
  float s0 = ps[(size_t)((m0 - 3) & 127) * 65536];
  float s1 = ps[(size_t)((m0 - 2) & 127) * 65536];
  float s2 = ps[(size_t)((m0 - 1) & 127) * 65536];
  float w0 = pw[(size_t)((m0 - 3) & 127) * 65536];
  float w1 = pw[(size_t)((m0 - 2) & 127) * 65536];
  float w2 = pw[(size_t)((m0 - 1) & 127) * 65536];
  for (int m = m0; m < m0 + 64; ++m) {
    const float s3 = ps[(size_t)m * 65536];
    const float w3 = pw[(size_t)m * 65536];
    const float y0 = Y0(s0, s1, s2, s3, w0, w1, w2, w3);
    const float y1 = Y1(s0, s1, s2, s3, w0, w1, w2, w3);
    po[(size_t)(2 * m) * 65536] = y0;
    po[(size_t)(2 * m + 1) * 65536] = y1;
    s0 = s1; s1 = s2; s2 = s3;
    w0 = w1; w1 = w2; w2 = w3;
  }
}

// ---------------- axis 2 (stride 256), in-place on buf ----------------
// Block stages a [256 rows x 32 cols] tile of one (b,d1) slice into LDS,
// then writes back the same region -> in-place safe (regions disjoint
// across blocks; all global reads precede the sync, writes follow it).
__global__ __launch_bounds__(256) void wav_axis2(float* __restrict__ buf,
                                                 const float* __restrict__ h) {
  __shared__ float tile[256][32];
  const int t = threadIdx.x;
  const int c = t & 31;
  const int g = t >> 5;                      // 0..7
  const size_t slice = (size_t)(blockIdx.x >> 3);
  const int col0 = (blockIdx.x & 7) * 32;
  float* __restrict__ p = buf + slice * 65536 + col0;
#pragma unroll
  for (int i = 0; i < 32; ++i) {
    const int r = i * 8 + g;
    tile[r][c] = p[r * 256 + c];
  }
  __syncthreads();
  FILT_DECL(h)
  const int m0 = g * 16;
  float s0 = tile[(m0 - 3) & 127][c];
  float s1 = tile[(m0 - 2) & 127][c];
  float s2 = tile[(m0 - 1) & 127][c];
  float w0 = tile[128 + ((m0 - 3) & 127)][c];
  float w1 = tile[128 + ((m0 - 2) & 127)][c];
  float w2 = tile[128 + ((m0 - 1) & 127)][c];
#pragma unroll
  for (int m = m0; m < m0 + 16; ++m) {
    const float s3 = tile[m][c];
    const float w3 = tile[128 + m][c];
    const float y0 = Y0(s0, s1, s2, s3, w0, w1, w2, w3);
    const float y1 = Y1(s0, s1, s2, s3, w0, w1, w2, w3);
    p[(2 * m) * 256 + c] = y0;
    p[(2 * m + 1) * 256 + c] = y1;
    s0 = s1; s1 = s2; s2 = s3;
    w0 = w1; w1 = w2; w2 = w3;
  }
}

// ---------------- axis 3 (contiguous), in-place on buf ----------------
// Block stages two full 256-element rows, computes, writes back same rows.
__global__ __launch_bounds__(256) void wav_axis3(float* __restrict__ buf,
                                                 const float* __restrict__ h) {
  __shared__ float tile[512];
  const int t = threadIdx.x;
  float* __restrict__ p = buf + (size_t)blockIdx.x * 512;
  tile[t] = p[t];
  tile[256 + t] = p[256 + t];
  __syncthreads();
  FILT_DECL(h)
  const int r = t >> 7;                       // which of the 2 rows
  const int m = t & 127;
  const float* __restrict__ line = tile + r * 256;
  const float s0 = line[(m - 3) & 127];
  const float s1 = line[(m - 2) & 127];
  const float s2 = line[(m - 1) & 127];
  const float s3 = line[m];
  const float w0 = line[128 + ((m - 3) & 127)];
  const float w1 = line[128 + ((m - 2) & 127)];
  const float w2 = line[128 + ((m - 1) & 127)];
  const float w3 = line[128 + m];
  float2 y;
  y.x = Y0(s0, s1, s2, s3, w0, w1, w2, w3);
  y.y = Y1(s0, s1, s2, s3, w0, w1, w2, w3);
  *reinterpret_cast<float2*>(p + r * 256 + 2 * m) = y;
}

extern "C" void kernel_launch(void* const* d_in, const int* in_sizes, int n_in,
                              void* d_out, int out_size, void* d_ws, size_t ws_size,
                              hipStream_t stream) {
  const float* x = (const float*)d_in[0];
  const float* h = (const float*)d_in[1];
  float* out = (float*)d_out;

  // axis 1: in -> out   (grid: 65536/256 inner blocks, 2 m-segments, 4 batches)
  wav_axis1<<<dim3(256, 2, 4), 256, 0, stream>>>(x, out, h);
  // axis 2: in-place    (1024 slices x 8 column tiles)
  wav_axis2<<<dim3(8192), 256, 0, stream>>>(out, h);
  // axis 3: in-place    (262144 rows / 2 rows per block)
  wav_axis3<<<dim3(131072), 256, 0, stream>>>(out, h);
}